// Round 6
// baseline (342.789 us; speedup 1.0000x reference)
//
#include <hip/hip_runtime.h>
#include <hip/hip_bf16.h>
#include <stdint.h>

// DequantingLinear: out[TOK,OUT] = x[TOK,IN] @ dequant(w_q,w_scales)^T + bias
// R6: faithful m201 8-phase. Phase=(M-half,K-slice): reads 8/4/8/4, 16 MFMA.
// K-split stage units (BM x 32cols, 16KB, 2 gloads), 1 unit staged/phase,
// vmcnt(6) at ph4/ph8 only (3 units in flight), 4-7 phase stage lead.

typedef __bf16 bf16;
typedef __bf16 bf16x8 __attribute__((ext_vector_type(8)));
typedef float f32x4 __attribute__((ext_vector_type(4)));

#define AS1 __attribute__((address_space(1)))
#define AS3 __attribute__((address_space(3)))

__device__ __forceinline__ void gload_lds16(const void* g, void* l) {
    __builtin_amdgcn_global_load_lds((AS1 void*)g, (AS3 void*)l, 16, 0, 0);
}

#define MFMA16(d, x, y) d = __builtin_amdgcn_mfma_f32_16x16x32_bf16(x, y, d, 0, 0, 0)

// ---------------- Pass 1a: dequantize w_q (int32) * scale -> bf16 ----------
__global__ __launch_bounds__(128) void k_dequant(
    const int* __restrict__ q, const float* __restrict__ sc,
    bf16* __restrict__ w, int IN) {
    const int row = blockIdx.y;
    const int k = (blockIdx.x * 128 + threadIdx.x) * 8;
    if (k >= IN) return;
    const float s = sc[(size_t)row * (IN >> 5) + (k >> 5)];
    const size_t base = (size_t)row * IN + k;
    const int4 q0 = *(const int4*)(q + base);
    const int4 q1 = *(const int4*)(q + base + 4);
    bf16x8 o;
    o[0] = (bf16)(q0.x * s); o[1] = (bf16)(q0.y * s);
    o[2] = (bf16)(q0.z * s); o[3] = (bf16)(q0.w * s);
    o[4] = (bf16)(q1.x * s); o[5] = (bf16)(q1.y * s);
    o[6] = (bf16)(q1.z * s); o[7] = (bf16)(q1.w * s);
    *(bf16x8*)(w + base) = o;
}

// ---------------- Pass 1b: x f32 -> bf16 -----------------------------------
__global__ __launch_bounds__(256) void k_cvt(
    const float* __restrict__ x, bf16* __restrict__ xb, long long n8) {
    long long i = (long long)blockIdx.x * 256 + threadIdx.x;
    const long long stride = (long long)gridDim.x * 256;
    for (; i < n8; i += stride) {
        const float4 a = *(const float4*)(x + i * 8);
        const float4 b = *(const float4*)(x + i * 8 + 4);
        bf16x8 o;
        o[0] = (bf16)a.x; o[1] = (bf16)a.y; o[2] = (bf16)a.z; o[3] = (bf16)a.w;
        o[4] = (bf16)b.x; o[5] = (bf16)b.y; o[6] = (bf16)b.z; o[7] = (bf16)b.w;
        *(bf16x8*)(xb + i * 8) = o;
    }
}

// ---------------- Pass 2: 256x256 bf16 GEMM, (h,ks)-phase schedule ---------
// 512 thr = 8 waves (wm=wv>>2, wn=wv&3); wave out 128x64; acc[8][4].
// Buf (64KB): A-k0 @0, A-k1 @16384, B-k0 @32768, B-k1 @49152 (units 16KB).
// Unit layout: logical (frow 0..255, c4 0..3 of 16B) at LDSrow=frow>>1,
// chunk = (((frow&1)<<2)|c4) ^ (LDSrow&7), byte = LDSrow*128 + chunk*16.
// Bijective, 8 lanes/bank-quad on ds_read_b128, gload-linear dest.
// Phase (h,ks): read pa[4] (+pb[4] when ks enters), 16 MFMA acc[h*4+m][n].
// Stages: 1 unit/phase -> vmcnt(6) at ph4/ph8 covers all reads (FIFO-sim'd).
__global__ __launch_bounds__(512, 2) void k_gemm8p(
    const bf16* __restrict__ A, const bf16* __restrict__ B,
    const float* __restrict__ bias, float* __restrict__ C,
    int M, int N, int K) {
    __shared__ __align__(16) char lds[131072];
    const int tid = threadIdx.x;
    const int wv = tid >> 6, ln = tid & 63;
    const int wm = wv >> 2, wn = wv & 3;
    const int nbn = N >> 8;
    const int nwg = gridDim.x;
    const int q8 = nwg >> 3, r8 = nwg & 7;
    const int xcd = blockIdx.x & 7, lin = blockIdx.x >> 3;
    const int swz = (xcd < r8 ? xcd * (q8 + 1)
                              : r8 * (q8 + 1) + (xcd - r8) * q8) + lin;
    const int bm = swz / nbn, bn = swz % nbn;

    const size_t rowb = (size_t)K * 2;
    // staging source map: lane slot L in unit -> logical (frow, c4)
    const int L0 = tid, L1 = tid + 512;
    const int x0 = (L0 & 7) ^ ((L0 >> 3) & 7);
    const int x1 = (L1 & 7) ^ ((L1 >> 3) & 7);
    const int fr0 = ((L0 >> 3) << 1) | (x0 >> 2), c40 = x0 & 3;
    const int fr1 = ((L1 >> 3) << 1) | (x1 >> 2), c41 = x1 & 3;
    const char* Asrc0 = (const char*)A + ((size_t)(bm << 8) + fr0) * rowb + c40 * 16;
    const char* Asrc1 = (const char*)A + ((size_t)(bm << 8) + fr1) * rowb + c41 * 16;
    const char* Bsrc0 = (const char*)B + ((size_t)(bn << 8) + fr0) * rowb + c40 * 16;
    const char* Bsrc1 = (const char*)B + ((size_t)(bn << 8) + fr1) * rowb + c41 * 16;
    const int ldsw = wv << 10;

#define STG(bb_, uo_, kt_, P_) do {                                           \
        const size_t kb_ = (size_t)(kt_) << 1;                                \
        gload_lds16(P_##src0 + kb_, lds + (bb_) + (uo_) + ldsw);              \
        gload_lds16(P_##src1 + kb_, lds + (bb_) + (uo_) + 8192 + ldsw);       \
    } while (0)

    // ds_read addressing: chunk is per-lane constant
    const int chunk = (((ln & 1) << 2) | (ln >> 4)) ^ ((ln >> 1) & 7);
    const int aoff = (wm << 13) + (((ln & 15) >> 1) << 7) + (chunk << 4);
    const int boff = (wn << 12) + (((ln & 15) >> 1) << 7) + (chunk << 4);

    f32x4 acc[8][4] = {};
    bf16x8 pb[4];

#define BAR __builtin_amdgcn_s_barrier()
#define VMW6 asm volatile("s_waitcnt vmcnt(6)" ::: "memory")
#define VMW0 asm volatile("s_waitcnt vmcnt(0)" ::: "memory")
#define NOST (void)0

#define PHASE(bb_, h_, ks_, RDB_, STAGE_STMT, ENDW_STMT) do {                 \
        const char* base_ = lds + (bb_) + (ks_) * 16384;                      \
        bf16x8 pa_[4];                                                        \
        _Pragma("unroll")                                                     \
        for (int m = 0; m < 4; ++m)                                           \
            pa_[m] = *(const bf16x8*)(base_ + ((h_) << 12) + aoff + (m << 10)); \
        if (RDB_) {                                                           \
            _Pragma("unroll")                                                 \
            for (int n = 0; n < 4; ++n)                                       \
                pb[n] = *(const bf16x8*)(base_ + 32768 + boff + (n << 10));   \
        }                                                                     \
        STAGE_STMT;                                                           \
        BAR;                                                                  \
        asm volatile("s_waitcnt lgkmcnt(0)" ::: "memory");                    \
        __builtin_amdgcn_s_setprio(1);                                        \
        _Pragma("unroll")                                                     \
        for (int m = 0; m < 4; ++m)                                           \
            _Pragma("unroll")                                                 \
            for (int n = 0; n < 4; ++n)                                       \
                MFMA16(acc[(h_) * 4 + m][n], pa_[m], pb[n]);                  \
        __builtin_amdgcn_s_setprio(0);                                        \
        ENDW_STMT;                                                            \
        BAR;                                                                  \
    } while (0)

    // ---- prologue: tile0 -> buf0 (4 units); tile1 -> buf1 (B-k0,A-k0,B-k1)
    STG(0, 0,     0,  A);
    STG(0, 16384, 32, A);
    STG(0, 32768, 0,  B);
    STG(0, 49152, 32, B);
    STG(65536, 32768, 64, B);
    STG(65536, 0,     64, A);
    STG(65536, 49152, 96, B);
    VMW6;  // tile0 resident; tile1's 3 units (6 loads) in flight
    BAR;

    const int NI = K >> 7;
    for (int j = 0; j < NI - 1; ++j) {
        const int kO = (j << 7) + 64;    // tile 2j+1
        const int kE = (j << 7) + 128;   // tile 2j+2
        const int kN = (j << 7) + 192;   // tile 2j+3
        PHASE(0,     0, 0, 1, STG(65536, 16384, kO + 32, A), NOST);  // ph1
        PHASE(0,     1, 0, 0, STG(0,     32768, kE,      B), NOST);  // ph2
        PHASE(0,     0, 1, 1, STG(0,     0,     kE,      A), NOST);  // ph3
        PHASE(0,     1, 1, 0, STG(0,     49152, kE + 32, B), VMW6);  // ph4
        PHASE(65536, 0, 0, 1, STG(0,     16384, kE + 32, A), NOST);  // ph5
        PHASE(65536, 1, 0, 0, STG(65536, 32768, kN,      B), NOST);  // ph6
        PHASE(65536, 0, 1, 1, STG(65536, 0,     kN,      A), NOST);  // ph7
        PHASE(65536, 1, 1, 0, STG(65536, 49152, kN + 32, B), VMW6);  // ph8
    }
    {   // last iteration: finish tile NT-1 (A-k1 at ph1), drain at ph4
        const int kO = ((NI - 1) << 7) + 64;
        PHASE(0,     0, 0, 1, STG(65536, 16384, kO + 32, A), NOST);
        PHASE(0,     1, 0, 0, NOST,                          NOST);
        PHASE(0,     0, 1, 1, NOST,                          NOST);
        PHASE(0,     1, 1, 0, NOST,                          VMW0);
        PHASE(65536, 0, 0, 1, NOST,                          NOST);
        PHASE(65536, 1, 0, 0, NOST,                          NOST);
        PHASE(65536, 0, 1, 1, NOST,                          NOST);
        PHASE(65536, 1, 1, 0, NOST,                          NOST);
    }
#undef PHASE
#undef STG

    // ---- epilogue: D layout col=lane&15, row=(lane>>4)*4+reg
    const int erow = (bm << 8) + (wm << 7) + ((ln >> 4) << 2);
    const int ecol = (bn << 8) + (wn << 6) + (ln & 15);
    float bv[4];
#pragma unroll
    for (int n = 0; n < 4; ++n) bv[n] = bias[ecol + (n << 4)];
#pragma unroll
    for (int m = 0; m < 8; ++m)
#pragma unroll
        for (int r = 0; r < 4; ++r) {
            float* Crow = C + (size_t)(erow + (m << 4) + r) * N + ecol;
#pragma unroll
            for (int n = 0; n < 4; ++n)
                Crow[n << 4] = acc[m][n][r] + bv[n];
        }
}

// ---------------- Fallback: fused dequant+GEMM (no workspace) --------------
__global__ __launch_bounds__(256) void k_fused(
    const float* __restrict__ X, const int* __restrict__ Q,
    const float* __restrict__ SC, const float* __restrict__ bias,
    float* __restrict__ C, int M, int N, int K) {
    __shared__ __align__(16) bf16 sA[128 * 32];
    __shared__ __align__(16) bf16 sB[128 * 32];
    const int tid = threadIdx.x;
    const int wv = tid >> 6;
    const int ln = tid & 63;
    const int nbn = N >> 7;
    const int nwg = gridDim.x;
    const int q8 = nwg >> 3, r8 = nwg & 7;
    const int xcd = blockIdx.x & 7, lin = blockIdx.x >> 3;
    const int swz = (xcd < r8 ? xcd * (q8 + 1)
                              : r8 * (q8 + 1) + (xcd - r8) * q8) + lin;
    const int bm = swz / nbn, bn = swz % nbn;
    const int wr = (wv >> 1) << 6;
    const int wc = (wv & 1) << 6;
    const int srow = tid >> 1;
    const int sk = (tid & 1) << 4;

    f32x4 acc[4][4] = {};
    const float* xrow = X + (size_t)((bm << 7) + srow) * K + sk;
    const int* qrow = Q + (size_t)((bn << 7) + srow) * K + sk;
    const float* scrow = SC + (size_t)((bn << 7) + srow) * (K >> 5);

    for (int kt = 0; kt < K; kt += 32) {
        const float4 a0 = *(const float4*)(xrow + kt);
        const float4 a1 = *(const float4*)(xrow + kt + 4);
        const float4 a2 = *(const float4*)(xrow + kt + 8);
        const float4 a3 = *(const float4*)(xrow + kt + 12);
        const int4 q0 = *(const int4*)(qrow + kt);
        const int4 q1 = *(const int4*)(qrow + kt + 4);
        const int4 q2 = *(const int4*)(qrow + kt + 8);
        const int4 q3 = *(const int4*)(qrow + kt + 12);
        const float s = scrow[(kt + sk) >> 5];
        bf16x8 wa0, wa1, wb0, wb1;
        wa0[0] = (bf16)a0.x; wa0[1] = (bf16)a0.y; wa0[2] = (bf16)a0.z; wa0[3] = (bf16)a0.w;
        wa0[4] = (bf16)a1.x; wa0[5] = (bf16)a1.y; wa0[6] = (bf16)a1.z; wa0[7] = (bf16)a1.w;
        wa1[0] = (bf16)a2.x; wa1[1] = (bf16)a2.y; wa1[2] = (bf16)a2.z; wa1[3] = (bf16)a2.w;
        wa1[4] = (bf16)a3.x; wa1[5] = (bf16)a3.y; wa1[6] = (bf16)a3.z; wa1[7] = (bf16)a3.w;
        wb0[0] = (bf16)(q0.x * s); wb0[1] = (bf16)(q0.y * s);
        wb0[2] = (bf16)(q0.z * s); wb0[3] = (bf16)(q0.w * s);
        wb0[4] = (bf16)(q1.x * s); wb0[5] = (bf16)(q1.y * s);
        wb0[6] = (bf16)(q1.z * s); wb0[7] = (bf16)(q1.w * s);
        wb1[0] = (bf16)(q2.x * s); wb1[1] = (bf16)(q2.y * s);
        wb1[2] = (bf16)(q2.z * s); wb1[3] = (bf16)(q2.w * s);
        wb1[4] = (bf16)(q3.x * s); wb1[5] = (bf16)(q3.y * s);
        wb1[6] = (bf16)(q3.z * s); wb1[7] = (bf16)(q3.w * s);
        __syncthreads();
        *(bf16x8*)(sA + srow * 32 + sk) = wa0;
        *(bf16x8*)(sA + srow * 32 + sk + 8) = wa1;
        *(bf16x8*)(sB + srow * 32 + sk) = wb0;
        *(bf16x8*)(sB + srow * 32 + sk + 8) = wb1;
        __syncthreads();

        bf16x8 af[4], bg[4];
#pragma unroll
        for (int m = 0; m < 4; ++m)
            af[m] = *(const bf16x8*)(sA + ((wr + (m << 4) + (ln & 15)) << 5) +
                                     ((ln >> 4) << 3));
#pragma unroll
        for (int n = 0; n < 4; ++n)
            bg[n] = *(const bf16x8*)(sB + ((wc + (n << 4) + (ln & 15)) << 5) +
                                     ((ln >> 4) << 3));
#pragma unroll
        for (int m = 0; m < 4; ++m)
#pragma unroll
            for (int n = 0; n < 4; ++n)
                acc[m][n] = __builtin_amdgcn_mfma_f32_16x16x32_bf16(
                    af[m], bg[n], acc[m][n], 0, 0, 0);
    }

    float bv[4];
#pragma unroll
    for (int n = 0; n < 4; ++n)
        bv[n] = bias[(bn << 7) + wc + (n << 4) + (ln & 15)];
#pragma unroll
    for (int m = 0; m < 4; ++m) {
        const int grow0 = (bm << 7) + wr + (m << 4) + ((ln >> 4) << 2);
#pragma unroll
        for (int r = 0; r < 4; ++r) {
            float* Crow = C + (size_t)(grow0 + r) * N;
#pragma unroll
            for (int n = 0; n < 4; ++n)
                Crow[(bn << 7) + wc + (n << 4) + (ln & 15)] =
                    acc[m][n][r] + bv[n];
        }
    }
}

extern "C" void kernel_launch(void* const* d_in, const int* in_sizes, int n_in,
                              void* d_out, int out_size, void* d_ws, size_t ws_size,
                              hipStream_t stream) {
    const float* x = (const float*)d_in[0];
    const int* wq = (const int*)d_in[1];
    const float* sc = (const float*)d_in[2];
    const float* bias = (const float*)d_in[3];
    float* out = (float*)d_out;

    const long long xN = in_sizes[0];  // TOK*IN
    const long long wN = in_sizes[1];  // OUT*IN
    const int OUT = in_sizes[3];       // bias length
    const int IN = (int)(wN / OUT);
    const int TOK = (int)(xN / IN);
    const int M = TOK, N = OUT, K = IN;

    const size_t wb_bytes = (size_t)wN * 2;
    const size_t xb_bytes = (size_t)xN * 2;
    const bool ok8p = (M % 256 == 0) && (N % 256 == 0) && (K % 128 == 0) &&
                      (K >= 256);

    if (ok8p && ws_size >= wb_bytes + xb_bytes) {
        bf16* Wb = (bf16*)d_ws;
        bf16* Xb = (bf16*)((char*)d_ws + wb_bytes);
        dim3 dq_grid((IN / 8 + 127) / 128, OUT);
        k_dequant<<<dq_grid, 128, 0, stream>>>(wq, sc, Wb, IN);
        const long long n8 = xN / 8;
        int cvt_blocks = (int)((n8 + 255) / 256);
        if (cvt_blocks > 2048) cvt_blocks = 2048;
        k_cvt<<<cvt_blocks, 256, 0, stream>>>(x, Xb, n8);
        const int grid = (M / 256) * (N / 256);
        k_gemm8p<<<grid, 512, 0, stream>>>(Xb, Wb, bias, out, M, N, K);
    } else {
        const int grid = (M / 128) * (N / 128);
        k_fused<<<grid, 256, 0, stream>>>(x, wq, sc, bias, out, M, N, K);
    }
}

// Round 7
// 340.794 us; speedup vs baseline: 1.0059x; 1.0059x over previous
//
#include <hip/hip_runtime.h>
#include <hip/hip_bf16.h>
#include <stdint.h>

// DequantingLinear: out[TOK,OUT] = x[TOK,IN] @ dequant(w_q,w_scales)^T + bias
// R7: 8-phase with REGISTER-PIPELINED operands: reads(p+1) issue before
// MFMA(p) in the same inter-barrier window, so the LDS drain of the next
// phase's fragments overlaps this phase's MFMA. Single barrier per phase,
// counted vmcnt(8) at even-phase starts (5-6 phase stage lead), compiler-
// managed counted lgkm (no inline lgkm -> no rule-18 hazard).

typedef __bf16 bf16;
typedef __bf16 bf16x8 __attribute__((ext_vector_type(8)));
typedef float f32x4 __attribute__((ext_vector_type(4)));

#define AS1 __attribute__((address_space(1)))
#define AS3 __attribute__((address_space(3)))

__device__ __forceinline__ void gload_lds16(const void* g, void* l) {
    __builtin_amdgcn_global_load_lds((AS1 void*)g, (AS3 void*)l, 16, 0, 0);
}

#define MFMA16(d, x, y) d = __builtin_amdgcn_mfma_f32_16x16x32_bf16(x, y, d, 0, 0, 0)

// ---------------- Pass 1a: dequantize w_q (int32) * scale -> bf16 ----------
__global__ __launch_bounds__(128) void k_dequant(
    const int* __restrict__ q, const float* __restrict__ sc,
    bf16* __restrict__ w, int IN) {
    const int row = blockIdx.y;
    const int k = (blockIdx.x * 128 + threadIdx.x) * 8;
    if (k >= IN) return;
    const float s = sc[(size_t)row * (IN >> 5) + (k >> 5)];
    const size_t base = (size_t)row * IN + k;
    const int4 q0 = *(const int4*)(q + base);
    const int4 q1 = *(const int4*)(q + base + 4);
    bf16x8 o;
    o[0] = (bf16)(q0.x * s); o[1] = (bf16)(q0.y * s);
    o[2] = (bf16)(q0.z * s); o[3] = (bf16)(q0.w * s);
    o[4] = (bf16)(q1.x * s); o[5] = (bf16)(q1.y * s);
    o[6] = (bf16)(q1.z * s); o[7] = (bf16)(q1.w * s);
    *(bf16x8*)(w + base) = o;
}

// ---------------- Pass 1b: x f32 -> bf16 -----------------------------------
__global__ __launch_bounds__(256) void k_cvt(
    const float* __restrict__ x, bf16* __restrict__ xb, long long n8) {
    long long i = (long long)blockIdx.x * 256 + threadIdx.x;
    const long long stride = (long long)gridDim.x * 256;
    for (; i < n8; i += stride) {
        const float4 a = *(const float4*)(x + i * 8);
        const float4 b = *(const float4*)(x + i * 8 + 4);
        bf16x8 o;
        o[0] = (bf16)a.x; o[1] = (bf16)a.y; o[2] = (bf16)a.z; o[3] = (bf16)a.w;
        o[4] = (bf16)b.x; o[5] = (bf16)b.y; o[6] = (bf16)b.z; o[7] = (bf16)b.w;
        *(bf16x8*)(xb + i * 8) = o;
    }
}

// ---------------- Pass 2: 256x256 bf16 GEMM, reg-pipelined 8-phase ---------
// 512 thr = 8 waves (wm=wv>>2, wn=wv&3); wave out 128x64; acc[8][4].
// LDS buf{0,1} @ {0,65536}: A-k0 @0, A-k1 @16384, B-k0 @32768, B-k1 @49152.
// Unit layout (16KB, verified R6): frow,c4 -> LDSrow=frow>>1,
// chunk=(((frow&1)<<2)|c4)^(LDSrow&7). Stage unit = 2 gload_lds.
// Phase p block: [vmcnt(8) if even] BAR; reads(p+1)->alt regs; stage; MFMA(p).
// Stage FIFO (per iter): ph1 A_O_k1 | ph2 B_E'k0 ph3 A_E'k0 ph4 B_E'k1
// ph5 A_E'k1 | ph6 B_O'k0 ph7 A_O'k0 ph8 B_O'k1. vmcnt(8) at even-phase
// start drains exactly the 2 units that phase's reads touch (5-6 ph lead).
__global__ __launch_bounds__(512, 2) void k_gemm8p(
    const bf16* __restrict__ A, const bf16* __restrict__ B,
    const float* __restrict__ bias, float* __restrict__ C,
    int M, int N, int K) {
    __shared__ __align__(16) char lds[131072];
    const int tid = threadIdx.x;
    const int wv = tid >> 6, ln = tid & 63;
    const int wm = wv >> 2, wn = wv & 3;
    const int nbn = N >> 8;
    const int nwg = gridDim.x;
    const int q8 = nwg >> 3, r8 = nwg & 7;
    const int xcd = blockIdx.x & 7, lin = blockIdx.x >> 3;
    const int swz = (xcd < r8 ? xcd * (q8 + 1)
                              : r8 * (q8 + 1) + (xcd - r8) * q8) + lin;
    const int bm = swz / nbn, bn = swz % nbn;

    const size_t rowb = (size_t)K * 2;
    // staging source map: lane slot L in unit -> logical (frow, c4), inverse
    // of the LDS swizzle so gload's linear dest yields the swizzled layout
    const int L0 = tid, L1 = tid + 512;
    const int x0 = (L0 & 7) ^ ((L0 >> 3) & 7);
    const int x1 = (L1 & 7) ^ ((L1 >> 3) & 7);
    const int fr0 = ((L0 >> 3) << 1) | (x0 >> 2), c40 = x0 & 3;
    const int fr1 = ((L1 >> 3) << 1) | (x1 >> 2), c41 = x1 & 3;
    const char* Asrc0 = (const char*)A + ((size_t)(bm << 8) + fr0) * rowb + c40 * 16;
    const char* Asrc1 = (const char*)A + ((size_t)(bm << 8) + fr1) * rowb + c41 * 16;
    const char* Bsrc0 = (const char*)B + ((size_t)(bn << 8) + fr0) * rowb + c40 * 16;
    const char* Bsrc1 = (const char*)B + ((size_t)(bn << 8) + fr1) * rowb + c41 * 16;
    const int ldsw = wv << 10;

#define STG(bb_, uo_, kt_, P_) do {                                           \
        const size_t kb_ = (size_t)(kt_) << 1;                                \
        gload_lds16(P_##src0 + kb_, lds + (bb_) + (uo_) + ldsw);              \
        gload_lds16(P_##src1 + kb_, lds + (bb_) + (uo_) + 8192 + ldsw);       \
    } while (0)

    // ds_read addressing (verified R6): chunk per-lane constant
    const int chunk = (((ln & 1) << 2) | (ln >> 4)) ^ ((ln >> 1) & 7);
    const int aoff = (wm << 13) + (((ln & 15) >> 1) << 7) + (chunk << 4);
    const int boff = (wn << 12) + (((ln & 15) >> 1) << 7) + (chunk << 4);

    f32x4 acc[8][4] = {};
    bf16x8 pa0[4], pa1[4], pb0[4], pb1[4];

#define RDA4(PA_, bb_, ks_, h_) do { _Pragma("unroll")                        \
        for (int m = 0; m < 4; ++m)                                           \
            PA_[m] = *(const bf16x8*)(lds + (bb_) + (ks_) * 16384 +           \
                                      ((h_) << 12) + aoff + (m << 10));       \
    } while (0)
#define RDB4(PB_, bb_, ks_) do { _Pragma("unroll")                            \
        for (int n = 0; n < 4; ++n)                                           \
            PB_[n] = *(const bf16x8*)(lds + (bb_) + (ks_) * 16384 + 32768 +   \
                                      boff + (n << 10));                      \
    } while (0)
#define MF(h_, PA_, PB_) do {                                                 \
        __builtin_amdgcn_s_setprio(1);                                        \
        _Pragma("unroll") for (int m = 0; m < 4; ++m)                         \
        _Pragma("unroll") for (int n = 0; n < 4; ++n)                         \
            MFMA16(acc[(h_) * 4 + m][n], PA_[m], PB_[n]);                     \
        __builtin_amdgcn_s_setprio(0);                                        \
    } while (0)

#define BAR __builtin_amdgcn_s_barrier()
#define VMW8 asm volatile("s_waitcnt vmcnt(8)" ::: "memory")
#define VMW4 asm volatile("s_waitcnt vmcnt(4)" ::: "memory")
#define VMW10 asm volatile("s_waitcnt vmcnt(10)" ::: "memory")
#define VMW0 asm volatile("s_waitcnt vmcnt(0)" ::: "memory")

    // ---- prologue: FIFO = A0k0,B0k0 | B0k1,A0k1,B1k0,A1k0,B1k1 (14 loads)
    STG(0, 0,     0,  A);   // A0 k0
    STG(0, 32768, 0,  B);   // B0 k0
    STG(0, 49152, 32, B);   // B0 k1   (plays "prev-ph4")
    STG(0, 16384, 32, A);   // A0 k1   ("prev-ph5")
    STG(65536, 32768, 64, B);  // B1 k0 ("prev-ph6")
    STG(65536, 0,     64, A);  // A1 k0 ("prev-ph7")
    STG(65536, 49152, 96, B);  // B1 k1 ("prev-ph8")
    VMW10;  // drain A0k0,B0k0; 10 loads (5 units) stay in flight
    BAR;
    RDA4(pa0, 0, 0, 0);  // reads(ph1): A_E_k0 h0
    RDB4(pb0, 0, 0);     //             B_E_k0

    const int NI = K >> 7;
#pragma unroll 1
    for (int j = 0; j < NI - 1; ++j) {
        const int kO = (j << 7) + 64, kE2 = kO + 64, kO2 = kE2 + 64;
        // ph1: MFMA(E,k0,h0)
        BAR;  RDA4(pa1, 0, 0, 1);                      STG(65536, 16384, kO + 32, A);  MF(0, pa0, pb0);
        // ph2: MFMA(E,k0,h1)
        VMW8; BAR; RDA4(pa0, 0, 1, 0); RDB4(pb1, 0, 1); STG(0, 32768, kE2, B);         MF(1, pa1, pb0);
        // ph3: MFMA(E,k1,h0)
        BAR;  RDA4(pa1, 0, 1, 1);                      STG(0, 0, kE2, A);              MF(0, pa0, pb1);
        // ph4: MFMA(E,k1,h1)
        VMW8; BAR; RDA4(pa0, 65536, 0, 0); RDB4(pb0, 65536, 0); STG(0, 49152, kE2 + 32, B); MF(1, pa1, pb1);
        // ph5: MFMA(O,k0,h0)
        BAR;  RDA4(pa1, 65536, 0, 1);                  STG(0, 16384, kE2 + 32, A);     MF(0, pa0, pb0);
        // ph6: MFMA(O,k0,h1)
        VMW8; BAR; RDA4(pa0, 65536, 1, 0); RDB4(pb1, 65536, 1); STG(65536, 32768, kO2, B); MF(1, pa1, pb0);
        // ph7: MFMA(O,k1,h0)
        BAR;  RDA4(pa1, 65536, 1, 1);                  STG(65536, 0, kO2, A);          MF(0, pa0, pb1);
        // ph8: MFMA(O,k1,h1)
        VMW8; BAR; RDA4(pa0, 0, 0, 0); RDB4(pb0, 0, 0); STG(65536, 49152, kO2 + 32, B); MF(1, pa1, pb1);
    }
    {   // peeled last iteration (tiles E=buf0, O=buf1; only A_O_k1 staged)
        const int kO = ((NI - 1) << 7) + 64;
        BAR;  RDA4(pa1, 0, 0, 1);                      STG(65536, 16384, kO + 32, A);  MF(0, pa0, pb0);
        VMW8; BAR; RDA4(pa0, 0, 1, 0); RDB4(pb1, 0, 1);                                MF(1, pa1, pb0);
        BAR;  RDA4(pa1, 0, 1, 1);                                                     MF(0, pa0, pb1);
        VMW4; BAR; RDA4(pa0, 65536, 0, 0); RDB4(pb0, 65536, 0);                        MF(1, pa1, pb1);
        BAR;  RDA4(pa1, 65536, 0, 1);                                                 MF(0, pa0, pb0);
        VMW0; BAR; RDA4(pa0, 65536, 1, 0); RDB4(pb1, 65536, 1);                        MF(1, pa1, pb0);
        BAR;  RDA4(pa1, 65536, 1, 1);                                                 MF(0, pa0, pb1);
        BAR;                                                                          MF(1, pa1, pb1);
    }
#undef STG
#undef RDA4
#undef RDB4
#undef MF

    // ---- epilogue: D layout col=lane&15, row=(lane>>4)*4+reg
    const int erow = (bm << 8) + (wm << 7) + ((ln >> 4) << 2);
    const int ecol = (bn << 8) + (wn << 6) + (ln & 15);
    float bv[4];
#pragma unroll
    for (int n = 0; n < 4; ++n) bv[n] = bias[ecol + (n << 4)];
#pragma unroll
    for (int m = 0; m < 8; ++m)
#pragma unroll
        for (int r = 0; r < 4; ++r) {
            float* Crow = C + (size_t)(erow + (m << 4) + r) * N + ecol;
#pragma unroll
            for (int n = 0; n < 4; ++n)
                Crow[n << 4] = acc[m][n][r] + bv[n];
        }
}

// ---------------- Fallback: fused dequant+GEMM (no workspace) --------------
__global__ __launch_bounds__(256) void k_fused(
    const float* __restrict__ X, const int* __restrict__ Q,
    const float* __restrict__ SC, const float* __restrict__ bias,
    float* __restrict__ C, int M, int N, int K) {
    __shared__ __align__(16) bf16 sA[128 * 32];
    __shared__ __align__(16) bf16 sB[128 * 32];
    const int tid = threadIdx.x;
    const int wv = tid >> 6;
    const int ln = tid & 63;
    const int nbn = N >> 7;
    const int nwg = gridDim.x;
    const int q8 = nwg >> 3, r8 = nwg & 7;
    const int xcd = blockIdx.x & 7, lin = blockIdx.x >> 3;
    const int swz = (xcd < r8 ? xcd * (q8 + 1)
                              : r8 * (q8 + 1) + (xcd - r8) * q8) + lin;
    const int bm = swz / nbn, bn = swz % nbn;
    const int wr = (wv >> 1) << 6;
    const int wc = (wv & 1) << 6;
    const int srow = tid >> 1;
    const int sk = (tid & 1) << 4;

    f32x4 acc[4][4] = {};
    const float* xrow = X + (size_t)((bm << 7) + srow) * K + sk;
    const int* qrow = Q + (size_t)((bn << 7) + srow) * K + sk;
    const float* scrow = SC + (size_t)((bn << 7) + srow) * (K >> 5);

    for (int kt = 0; kt < K; kt += 32) {
        const float4 a0 = *(const float4*)(xrow + kt);
        const float4 a1 = *(const float4*)(xrow + kt + 4);
        const float4 a2 = *(const float4*)(xrow + kt + 8);
        const float4 a3 = *(const float4*)(xrow + kt + 12);
        const int4 q0 = *(const int4*)(qrow + kt);
        const int4 q1 = *(const int4*)(qrow + kt + 4);
        const int4 q2 = *(const int4*)(qrow + kt + 8);
        const int4 q3 = *(const int4*)(qrow + kt + 12);
        const float s = scrow[(kt + sk) >> 5];
        bf16x8 wa0, wa1, wb0, wb1;
        wa0[0] = (bf16)a0.x; wa0[1] = (bf16)a0.y; wa0[2] = (bf16)a0.z; wa0[3] = (bf16)a0.w;
        wa0[4] = (bf16)a1.x; wa0[5] = (bf16)a1.y; wa0[6] = (bf16)a1.z; wa0[7] = (bf16)a1.w;
        wa1[0] = (bf16)a2.x; wa1[1] = (bf16)a2.y; wa1[2] = (bf16)a2.z; wa1[3] = (bf16)a2.w;
        wa1[4] = (bf16)a3.x; wa1[5] = (bf16)a3.y; wa1[6] = (bf16)a3.z; wa1[7] = (bf16)a3.w;
        wb0[0] = (bf16)(q0.x * s); wb0[1] = (bf16)(q0.y * s);
        wb0[2] = (bf16)(q0.z * s); wb0[3] = (bf16)(q0.w * s);
        wb0[4] = (bf16)(q1.x * s); wb0[5] = (bf16)(q1.y * s);
        wb0[6] = (bf16)(q1.z * s); wb0[7] = (bf16)(q1.w * s);
        wb1[0] = (bf16)(q2.x * s); wb1[1] = (bf16)(q2.y * s);
        wb1[2] = (bf16)(q2.z * s); wb1[3] = (bf16)(q2.w * s);
        wb1[4] = (bf16)(q3.x * s); wb1[5] = (bf16)(q3.y * s);
        wb1[6] = (bf16)(q3.z * s); wb1[7] = (bf16)(q3.w * s);
        __syncthreads();
        *(bf16x8*)(sA + srow * 32 + sk) = wa0;
        *(bf16x8*)(sA + srow * 32 + sk + 8) = wa1;
        *(bf16x8*)(sB + srow * 32 + sk) = wb0;
        *(bf16x8*)(sB + srow * 32 + sk + 8) = wb1;
        __syncthreads();

        bf16x8 af[4], bg[4];
#pragma unroll
        for (int m = 0; m < 4; ++m)
            af[m] = *(const bf16x8*)(sA + ((wr + (m << 4) + (ln & 15)) << 5) +
                                     ((ln >> 4) << 3));
#pragma unroll
        for (int n = 0; n < 4; ++n)
            bg[n] = *(const bf16x8*)(sB + ((wc + (n << 4) + (ln & 15)) << 5) +
                                     ((ln >> 4) << 3));
#pragma unroll
        for (int m = 0; m < 4; ++m)
#pragma unroll
            for (int n = 0; n < 4; ++n)
                acc[m][n] = __builtin_amdgcn_mfma_f32_16x16x32_bf16(
                    af[m], bg[n], acc[m][n], 0, 0, 0);
    }

    float bv[4];
#pragma unroll
    for (int n = 0; n < 4; ++n)
        bv[n] = bias[(bn << 7) + wc + (n << 4) + (ln & 15)];
#pragma unroll
    for (int m = 0; m < 4; ++m) {
        const int grow0 = (bm << 7) + wr + (m << 4) + ((ln >> 4) << 2);
#pragma unroll
        for (int r = 0; r < 4; ++r) {
            float* Crow = C + (size_t)(grow0 + r) * N;
#pragma unroll
            for (int n = 0; n < 4; ++n)
                Crow[(bn << 7) + wc + (n << 4) + (ln & 15)] =
                    acc[m][n][r] + bv[n];
        }
    }
}

extern "C" void kernel_launch(void* const* d_in, const int* in_sizes, int n_in,
                              void* d_out, int out_size, void* d_ws, size_t ws_size,
                              hipStream_t stream) {
    const float* x = (const float*)d_in[0];
    const int* wq = (const int*)d_in[1];
    const float* sc = (const float*)d_in[2];
    const float* bias = (const float*)d_in[3];
    float* out = (float*)d_out;

    const long long xN = in_sizes[0];  // TOK*IN
    const long long wN = in_sizes[1];  // OUT*IN
    const int OUT = in_sizes[3];       // bias length
    const int IN = (int)(wN / OUT);
    const int TOK = (int)(xN / IN);
    const int M = TOK, N = OUT, K = IN;

    const size_t wb_bytes = (size_t)wN * 2;
    const size_t xb_bytes = (size_t)xN * 2;
    const bool ok8p = (M % 256 == 0) && (N % 256 == 0) && (K % 128 == 0) &&
                      (K >= 256);

    if (ok8p && ws_size >= wb_bytes + xb_bytes) {
        bf16* Wb = (bf16*)d_ws;
        bf16* Xb = (bf16*)((char*)d_ws + wb_bytes);
        dim3 dq_grid((IN / 8 + 127) / 128, OUT);
        k_dequant<<<dq_grid, 128, 0, stream>>>(wq, sc, Wb, IN);
        const long long n8 = xN / 8;
        int cvt_blocks = (int)((n8 + 255) / 256);
        if (cvt_blocks > 2048) cvt_blocks = 2048;
        k_cvt<<<cvt_blocks, 256, 0, stream>>>(x, Xb, n8);
        const int grid = (M / 256) * (N / 256);
        k_gemm8p<<<grid, 512, 0, stream>>>(Xb, Wb, bias, out, M, N, K);
    } else {
        const int grid = (M / 128) * (N / 128);
        k_fused<<<grid, 256, 0, stream>>>(x, wq, sc, bias, out, M, N, K);
    }
}